// Round 3
// baseline (31.230 us; speedup 1.0000x reference)
//
#include <hip/hip_runtime.h>
#include <cmath>
#include <algorithm>

#ifndef M_PI
#define M_PI 3.14159265358979323846
#endif

// Problem geometry (fixed by reference setup_inputs): image (B=2,C=32,H=512,W=1024) f32
static constexpr int Hc  = 512;
static constexpr int Wc  = 1024;
static constexpr int H2c = 256;   // H/2 output rows
static constexpr int W2c = 512;   // W/2 output cols

// Per-output-row table packed as k:11 | pad:9 | t:4, passed by value (1 KB kernarg).
struct RowTab { unsigned int v[H2c]; };

// One block per (row r, pair of bc-planes). Both sub-problems share the same
// (k, pad, t) -> identical doubling trip count, every barrier covers 2x data.
__global__ __launch_bounds__(256) void sph_pool_kernel2(const float* __restrict__ in,
                                                        float* __restrict__ out,
                                                        const RowTab tab, int BC) {
    const int r   = blockIdx.x;        // 0..H2-1
    const int bc0 = 2 * blockIdx.y;    // first bc-plane
    const int bc1 = bc0 + 1;           // second (guarded if BC odd)
    const bool has1 = (bc1 < BC);
    const int tid = threadIdx.x;       // 0..255

    __shared__ float buf[2][2][Wc];    // [problem][ping-pong][W] = 16 KB

    const unsigned int tv = tab.v[r];  // scalar load from kernarg
    const int k   = tv & 0x7FF;
    const int pad = (tv >> 11) & 0x1FF;
    const int pw  = 1 << ((tv >> 20) & 0xF);   // 2^t

    const size_t plane = (size_t)Hc * (size_t)Wc;
    const float4* p0 = (const float4*)(in + (size_t)bc0 * plane + (size_t)(2 * r) * Wc);
    const float4* p1 = (const float4*)(in + (size_t)bc1 * plane + (size_t)(2 * r) * Wc);

    // 64 B of global loads in flight per thread before the first barrier.
    float4 a0 = p0[tid];
    float4 b0 = p0[tid + Wc / 4];
    float4 a1, b1;
    if (has1) { a1 = p1[tid]; b1 = p1[tid + Wc / 4]; }

    float4 m;
    m.x = fmaxf(a0.x, b0.x); m.y = fmaxf(a0.y, b0.y);
    m.z = fmaxf(a0.z, b0.z); m.w = fmaxf(a0.w, b0.w);
    ((float4*)buf[0][0])[tid] = m;
    if (has1) {
        m.x = fmaxf(a1.x, b1.x); m.y = fmaxf(a1.y, b1.y);
        m.z = fmaxf(a1.z, b1.z); m.w = fmaxf(a1.w, b1.w);
        ((float4*)buf[1][0])[tid] = m;
    }
    __syncthreads();

    // Doubling: after level `off`, buf[p][nxt][w] = max over [w, w+2*off-1] mod W
    int cur = 0;
    for (int off = 1; off < pw; off <<= 1) {   // uniform trip count within block
        #pragma unroll
        for (int i = 0; i < 4; ++i) {
            int w  = tid + i * 256;
            int w2 = (w + off) & (Wc - 1);
            buf[0][cur ^ 1][w] = fmaxf(buf[0][cur][w], buf[0][cur][w2]);
            buf[1][cur ^ 1][w] = fmaxf(buf[1][cur][w], buf[1][cur][w2]);
        }
        __syncthreads();
        cur ^= 1;
    }
    // Level-t table now in buf[p][cur]: value at w = max over [w, w+pw-1] mod W

    float* o0 = out + (size_t)bc0 * (size_t)(H2c * W2c) + (size_t)r * (size_t)W2c;
    float* o1 = o0 + (size_t)(H2c * W2c);
    #pragma unroll
    for (int i = 0; i < 2; ++i) {
        int j  = tid + i * 256;                    // output column
        int s1 = (2 * j - pad + Wc) & (Wc - 1);    // window start
        int s2 = (s1 + k - pw) & (Wc - 1);         // second lookup start
        o0[j] = fmaxf(buf[0][cur][s1], buf[0][cur][s2]);
        if (has1) o1[j] = fmaxf(buf[1][cur][s1], buf[1][cur][s2]);
    }
}

extern "C" void kernel_launch(void* const* d_in, const int* in_sizes, int n_in,
                              void* d_out, int out_size, void* d_ws, size_t ws_size,
                              hipStream_t stream) {
    const float* in = (const float*)d_in[0];
    float* out = (float*)d_out;
    const int BC = in_sizes[0] / (Hc * Wc);  // 64 for (2,32,512,1024)

    // Host-side table (double precision, matches numpy float64 semantics).
    // np.round = rint (ties-to-even); pad = int((k-2)/2+0.5) == (k-1)>>1 for k>=2;
    // t = floor(log2 k) == 31-clz(k). Row 0 boundary: c == -1 analytically; both
    // branches round to k=1024, so ulp-level libm divergence is harmless.
    RowTab tab;
    const double theta_sr = (double)Hc / M_PI;
    const double phi_sr   = (double)Wc / M_PI / 2.0;
    const double rad      = 1.0 / theta_sr;
    for (int r = 0; r < H2c; ++r) {
        double th  = (2.0 * r + 0.5) / theta_sr;
        double sth = std::sin(th);
        double cth = std::cos(th);
        double c   = (std::cos(rad) - cth * cth) / (sth * sth);
        double width = (c <= -1.0) ? (2.0 * M_PI) : (2.0 * std::acos(std::min(c, 1.0)));
        int k = (int)std::rint(width * phi_sr);
        k = std::min(std::max(k, 2), Wc);
        int pad = (k - 1) >> 1;
        int t = 31 - __builtin_clz((unsigned)k);
        tab.v[r] = (unsigned)k | ((unsigned)pad << 11) | ((unsigned)t << 20);
    }

    const int nPairs = (BC + 1) / 2;
    sph_pool_kernel2<<<dim3(H2c, nPairs), dim3(256), 0, stream>>>(in, out, tab, BC);
}

// Round 4
// 29.925 us; speedup vs baseline: 1.0436x; 1.0436x over previous
//
#include <hip/hip_runtime.h>
#include <cmath>
#include <algorithm>

#ifndef M_PI
#define M_PI 3.14159265358979323846
#endif

// Problem geometry (fixed by reference setup_inputs): image (B=2,C=32,H=512,W=1024) f32
static constexpr int Hc  = 512;
static constexpr int Wc  = 1024;
static constexpr int H2c = 256;   // H/2 output rows
static constexpr int W2c = 512;   // W/2 output cols

// Per-output-row table packed as k:11 | pad:9 | t:4, passed by value (1 KB kernarg).
struct RowTab { unsigned int v[H2c]; };

// One block per (bc, output row). Load pair of rows, rowmax into LDS,
// sparse-table doubling to level t (ping-pong), then 2-lookup window max.
// R3 post-mortem: 2-plane/block variant regressed (31.2 vs 30.5) — barriers are
// not the limiter; this 1-plane form measured 6.1 TB/s kernel-only (≈ m13 ceiling).
__global__ __launch_bounds__(256) void sph_pool_kernel(const float* __restrict__ in,
                                                       float* __restrict__ out,
                                                       const RowTab tab) {
    const int r   = blockIdx.x;   // 0..H2-1
    const int bc  = blockIdx.y;   // 0..B*C-1
    const int tid = threadIdx.x;  // 0..255

    __shared__ float bufA[Wc];
    __shared__ float bufB[Wc];

    const unsigned int tv = tab.v[r];          // scalar load from kernarg
    const int k   = tv & 0x7FF;
    const int pad = (tv >> 11) & 0x1FF;
    const int pw  = 1 << ((tv >> 20) & 0xF);   // 2^t

    // Global -> LDS: rowmax of rows 2r, 2r+1 (float4 coalesced, 8 KB contiguous)
    const float4* row0 = (const float4*)(in + (size_t)bc * (size_t)(Hc * Wc)
                                            + (size_t)(2 * r) * (size_t)Wc);
    float4 a = row0[tid];            // row 2r
    float4 b = row0[tid + Wc / 4];   // row 2r+1
    float4 m;
    m.x = fmaxf(a.x, b.x);
    m.y = fmaxf(a.y, b.y);
    m.z = fmaxf(a.z, b.z);
    m.w = fmaxf(a.w, b.w);
    ((float4*)bufA)[tid] = m;
    __syncthreads();

    // Doubling: after level with shift `off`, dst[w] = max over [w, w+2*off-1] mod W
    float* src = bufA;
    float* dst = bufB;
    for (int off = 1; off < pw; off <<= 1) {   // uniform trip count within block
        #pragma unroll
        for (int i = 0; i < 4; ++i) {
            int w = tid + i * 256;
            dst[w] = fmaxf(src[w], src[(w + off) & (Wc - 1)]);
        }
        __syncthreads();
        float* tmp = src; src = dst; dst = tmp;
    }
    // Level-t table now in src: src[w] = max over [w, w+pw-1] mod W

    float* out_row = out + (size_t)bc * (size_t)(H2c * W2c) + (size_t)r * (size_t)W2c;
    #pragma unroll
    for (int i = 0; i < 2; ++i) {
        int j = tid + i * 256;                     // output column
        int s1 = (2 * j - pad + Wc) & (Wc - 1);    // window start (pad <= 511 < Wc)
        int s2 = (s1 + k - pw) & (Wc - 1);         // second lookup start
        out_row[j] = fmaxf(src[s1], src[s2]);
    }
}

extern "C" void kernel_launch(void* const* d_in, const int* in_sizes, int n_in,
                              void* d_out, int out_size, void* d_ws, size_t ws_size,
                              hipStream_t stream) {
    const float* in = (const float*)d_in[0];
    float* out = (float*)d_out;
    const int BC = in_sizes[0] / (Hc * Wc);  // 64 for (2,32,512,1024)

    // Host-side table (double precision, matches numpy float64 semantics).
    // np.round = rint (ties-to-even); pad = int((k-2)/2+0.5) == (k-1)>>1 for k>=2;
    // t = floor(log2 k) == 31-clz(k). Row 0 boundary: c == -1 analytically; both
    // branches round to k=1024, so ulp-level libm divergence is harmless.
    RowTab tab;
    const double theta_sr = (double)Hc / M_PI;
    const double phi_sr   = (double)Wc / M_PI / 2.0;
    const double rad      = 1.0 / theta_sr;
    for (int r = 0; r < H2c; ++r) {
        double th  = (2.0 * r + 0.5) / theta_sr;
        double sth = std::sin(th);
        double cth = std::cos(th);
        double c   = (std::cos(rad) - cth * cth) / (sth * sth);
        double width = (c <= -1.0) ? (2.0 * M_PI) : (2.0 * std::acos(std::min(c, 1.0)));
        int k = (int)std::rint(width * phi_sr);
        k = std::min(std::max(k, 2), Wc);
        int pad = (k - 1) >> 1;
        int t = 31 - __builtin_clz((unsigned)k);
        tab.v[r] = (unsigned)k | ((unsigned)pad << 11) | ((unsigned)t << 20);
    }

    sph_pool_kernel<<<dim3(H2c, BC), dim3(256), 0, stream>>>(in, out, tab);
}